// Round 2
// baseline (171.280 us; speedup 1.0000x reference)
//
#include <hip/hip_runtime.h>
#include <math.h>

#define BB 8
#define NN 64
#define SS 128
#define DD 512
#define HH 8
#define DKK 64
#define TS 16
#define NT (SS / TS)

#define SENT_STRIDE (SS * DD)   // 65536 floats per sentence in out
#define Y_OFF  0                // row 0: final y (512 f)
#define Z_OFF  DD               // row 1: z (512 f)
#define XB_OFF (2 * DD)         // rows 2-9: xbar (8*512 f)

#define GLOBAL_AS(p) ((const __attribute__((address_space(1))) void*)(p))
#define LDS_AS(p)    ((__attribute__((address_space(3))) void*)(p))

// ---------------------------------------------------------------------------
// Kernel 0: fold Wk with sent_q: wk_t[h][d] = sum_k Wk[d, h*64+k] * sent_q[h,k]
// (bk is softmax-shift-invariant -> skipped)
// ---------------------------------------------------------------------------
__global__ void precompute_wk(const float* __restrict__ Wk,
                              const float* __restrict__ sq,
                              float* __restrict__ wk_t) {
    const int d = threadIdx.x;
    const int h = blockIdx.x;
    const float4* wrow = (const float4*)(Wk + (size_t)d * DD + h * DKK);
    const float4* sqv  = (const float4*)(sq + h * DKK);
    float acc = 0.f;
#pragma unroll
    for (int k = 0; k < DKK / 4; ++k) {
        float4 w = wrow[k], q = sqv[k];
        acc += w.x * q.x + w.y * q.y + w.z * q.z + w.w * q.w;
    }
    wk_t[h * DD + d] = acc;
}

// ---------------------------------------------------------------------------
// Kernel 1: per-sentence scores + exp weights + xbar. One block per (b,n).
// x streamed HBM->LDS once (global_load_lds, double-buffered).
// Writes normalized xbar to out rows 2-9 of the sentence's region.
// ---------------------------------------------------------------------------
__global__ __launch_bounds__(512, 4)
void k1_xbar(const float* __restrict__ x, const int* __restrict__ mask,
             const float* __restrict__ wk_t, float* __restrict__ outp)
{
    __shared__ float xl[2][TS][DD];   // 64 KB (2 x 32 KB tiles)
    __shared__ float wl[HH][SS];      // 4 KB exp-weights
    __shared__ float wsum_sh[HH];
    __shared__ int   ml[SS];

    const int bid  = blockIdx.x;
    const int t    = threadIdx.x;
    const int wave = t >> 6;
    const int lane = t & 63;
    const float* xs = x + (size_t)bid * SENT_STRIDE;

    if (t < SS) ml[t] = mask[bid * SS + t];

    // wk fragments in registers: lane owns dims d0..d0+7 for all 8 heads
    const int d0 = lane * 8;
    float4 wkA[HH], wkB[HH];
#pragma unroll
    for (int h = 0; h < HH; ++h) {
        wkA[h] = *(const float4*)(wk_t + h * DD + d0);
        wkB[h] = *(const float4*)(wk_t + h * DD + d0 + 4);
    }

    float acc[HH];
#pragma unroll
    for (int h = 0; h < HH; ++h) acc[h] = 0.f;

    // async stage of one 32KB tile: wave w copies its 4KB chunk (4 x 1KB calls)
    // LDS dest is wave-uniform base + lane*16 (linear), matching linear global src
#define STAGE(buf, tile)                                                        \
    do {                                                                        \
        const float* g_ = xs + (tile) * (TS * DD) + wave * 1024 + lane * 4;     \
        float* l_ = &xl[(buf)][0][0] + wave * 1024;                             \
        __builtin_amdgcn_global_load_lds(GLOBAL_AS(g_ +   0), LDS_AS(l_ +   0), 16, 0, 0); \
        __builtin_amdgcn_global_load_lds(GLOBAL_AS(g_ + 256), LDS_AS(l_ + 256), 16, 0, 0); \
        __builtin_amdgcn_global_load_lds(GLOBAL_AS(g_ + 512), LDS_AS(l_ + 512), 16, 0, 0); \
        __builtin_amdgcn_global_load_lds(GLOBAL_AS(g_ + 768), LDS_AS(l_ + 768), 16, 0, 0); \
    } while (0)

    STAGE(0, 0);

    for (int tile = 0; tile < NT; ++tile) {
        const int cur = tile & 1;
        __syncthreads();                       // drains vmcnt: xl[cur] ready, ml ready
        if (tile + 1 < NT) STAGE(cur ^ 1, tile + 1);   // async prefetch (in flight across mid-barrier)

        // ---- dots: wave handles tokens 2*wave, 2*wave+1 of this tile ----
#pragma unroll
        for (int j = 0; j < 2; ++j) {
            const int sl = wave * 2 + j;
            const int sg = tile * TS + sl;
            const float* xr = &xl[cur][sl][d0];
            float4 xa = *(const float4*)xr;
            float4 xb = *(const float4*)(xr + 4);
            float p[HH];
#pragma unroll
            for (int h = 0; h < HH; ++h)
                p[h] = xa.x * wkA[h].x + xa.y * wkA[h].y + xa.z * wkA[h].z + xa.w * wkA[h].w
                     + xb.x * wkB[h].x + xb.y * wkB[h].y + xb.z * wkB[h].z + xb.w * wkB[h].w;
            // 3 butterfly levels: every 8-lane group holds 8 partial sums (64 dims each)
#pragma unroll
            for (int off = 1; off <= 4; off <<= 1)
#pragma unroll
                for (int h = 0; h < HH; ++h)
                    p[h] += __shfl_xor(p[h], off, 64);
            // lane picks head (lane&7), 3 more levels reduce across the 8 groups
            const int hsel = lane & 7;
            float v = p[0];
#pragma unroll
            for (int h = 1; h < HH; ++h) v = (hsel == h) ? p[h] : v;
#pragma unroll
            for (int off = 8; off <= 32; off <<= 1)
                v += __shfl_xor(v, off, 64);
            if (lane < HH) {
                const float e = (ml[sg] == 0) ? 0.f : __expf(v * 0.125f);
                wl[lane][sg] = e;
            }
        }
        // wl visible to all, but do NOT drain vmcnt (keep prefetch in flight)
        asm volatile("s_waitcnt lgkmcnt(0)" ::: "memory");
        __builtin_amdgcn_s_barrier();

        // ---- accumulate: thread t owns dim t; two 8-token halves ----
#pragma unroll
        for (int half = 0; half < 2; ++half) {
            float xv[8];
#pragma unroll
            for (int s = 0; s < 8; ++s) xv[s] = xl[cur][half * 8 + s][t];
#pragma unroll
            for (int h = 0; h < HH; ++h) {
                const float* wp = &wl[h][tile * TS + half * 8];
                float4 w0 = *(const float4*)(wp);
                float4 w1 = *(const float4*)(wp + 4);
                acc[h] += w0.x * xv[0] + w0.y * xv[1] + w0.z * xv[2] + w0.w * xv[3]
                        + w1.x * xv[4] + w1.y * xv[5] + w1.z * xv[6] + w1.w * xv[7];
            }
        }
    }

    // per-head weight sums: wave h reduces wl[h][:]
    {
        float v = wl[wave][lane] + wl[wave][lane + 64];
#pragma unroll
        for (int off = 32; off > 0; off >>= 1)
            v += __shfl_xor(v, off, 64);
        if (lane == 0) wsum_sh[wave] = v;
    }
    __syncthreads();

    float* xb = outp + (size_t)bid * SENT_STRIDE + XB_OFF;
#pragma unroll
    for (int h = 0; h < HH; ++h)
        xb[h * DD + t] = acc[h] * (1.0f / wsum_sh[h]);
#undef STAGE
}

// ---------------------------------------------------------------------------
// Kernels 2/3: tiled 64x64 fp32 GEMM, M=512 rows (sentences, stride 65536),
// K=512, N-block = (bid&7)*64.  C[m][n] = bias[n] + sum_k A[m][k]*B[k][n].
// K2: A = Xbar (acolstride=512 selects head block), B = Wv  -> Z
// K3: A = Z    (acolstride=0),                      B = Wo  -> Y
// ---------------------------------------------------------------------------
__global__ __launch_bounds__(256)
void gemm64(const float* __restrict__ A, const int acolstride,
            const float* __restrict__ B, const float* __restrict__ bias,
            float* __restrict__ C)
{
    __shared__ float As[64][17];   // +1 pad -> 2-way (free) on column reads
    __shared__ float Bs[16][64];

    const int bid = blockIdx.x;
    const int nb  = bid & 7, mb = bid >> 3;
    const int tid = threadIdx.x;
    const int tr  = tid >> 4, tc = tid & 15;
    const int ar  = tid >> 2, aq = tid & 3;
    const int br  = tid >> 4, bc = tid & 15;

    const float* Ab = A + (size_t)(mb * 64) * SENT_STRIDE + nb * acolstride;
    const float* Bb = B + nb * 64;

    float ac[4][4];
#pragma unroll
    for (int i = 0; i < 4; ++i)
#pragma unroll
        for (int j = 0; j < 4; ++j) ac[i][j] = 0.f;

    for (int k0 = 0; k0 < DD; k0 += 16) {
        float4 av  = *(const float4*)(Ab + (size_t)ar * SENT_STRIDE + k0 + aq * 4);
        float4 bv4 = *(const float4*)(Bb + (size_t)(k0 + br) * DD + bc * 4);
        As[ar][aq * 4 + 0] = av.x;
        As[ar][aq * 4 + 1] = av.y;
        As[ar][aq * 4 + 2] = av.z;
        As[ar][aq * 4 + 3] = av.w;
        *(float4*)&Bs[br][bc * 4] = bv4;
        __syncthreads();
#pragma unroll
        for (int kk = 0; kk < 16; ++kk) {
            const float a0 = As[tr * 4 + 0][kk];
            const float a1 = As[tr * 4 + 1][kk];
            const float a2 = As[tr * 4 + 2][kk];
            const float a3 = As[tr * 4 + 3][kk];
            const float4 b4 = *(const float4*)&Bs[kk][tc * 4];
            ac[0][0] += a0 * b4.x; ac[0][1] += a0 * b4.y; ac[0][2] += a0 * b4.z; ac[0][3] += a0 * b4.w;
            ac[1][0] += a1 * b4.x; ac[1][1] += a1 * b4.y; ac[1][2] += a1 * b4.z; ac[1][3] += a1 * b4.w;
            ac[2][0] += a2 * b4.x; ac[2][1] += a2 * b4.y; ac[2][2] += a2 * b4.z; ac[2][3] += a2 * b4.w;
            ac[3][0] += a3 * b4.x; ac[3][1] += a3 * b4.y; ac[3][2] += a3 * b4.z; ac[3][3] += a3 * b4.w;
        }
        __syncthreads();
    }

    const float4 bb = *(const float4*)(bias + nb * 64 + tc * 4);
#pragma unroll
    for (int i = 0; i < 4; ++i) {
        float4 o;
        o.x = ac[i][0] + bb.x;
        o.y = ac[i][1] + bb.y;
        o.z = ac[i][2] + bb.z;
        o.w = ac[i][3] + bb.w;
        *(float4*)(C + (size_t)(mb * 64 + tr * 4 + i) * SENT_STRIDE + nb * 64 + tc * 4) = o;
    }
}

// ---------------------------------------------------------------------------
// Kernel 4: broadcast y (row 0 of each sentence region) to all 128 token rows.
// 4 blocks per sentence x 32 rows. Rewriting row 0 stores identical bytes.
// ---------------------------------------------------------------------------
__global__ __launch_bounds__(256)
void k4_broadcast(float* __restrict__ outp)
{
    const int sent = blockIdx.x >> 2, q = blockIdx.x & 3;
    float* base = outp + (size_t)sent * SENT_STRIDE;
    const int t = threadIdx.x;
    const int c = t & 127;                         // float4 column
    const float4 y = *(const float4*)(base + c * 4);   // row 0 holds Y
    const int r0 = q * 32 + (t >> 7);
    float* w0 = base + (size_t)r0 * DD + c * 4;
#pragma unroll
    for (int i = 0; i < 16; ++i)
        *(float4*)(w0 + (size_t)(i * 2) * DD) = y;
}

extern "C" void kernel_launch(void* const* d_in, const int* in_sizes, int n_in,
                              void* d_out, int out_size, void* d_ws, size_t ws_size,
                              hipStream_t stream) {
    const float* x    = (const float*)d_in[0];
    const int*   mask = (const int*)  d_in[1];
    // d_in[2]=Wq, d_in[3]=bq dead (token softmax over singleton); d_in[5]=bk shift-invariant
    const float* Wk   = (const float*)d_in[4];
    const float* Wv   = (const float*)d_in[6];
    const float* bv   = (const float*)d_in[7];
    const float* sq   = (const float*)d_in[8];
    const float* Wo   = (const float*)d_in[9];
    const float* bo   = (const float*)d_in[10];
    float* out  = (float*)d_out;
    float* wk_t = (float*)d_ws;   // 16 KB

    precompute_wk<<<HH, DD, 0, stream>>>(Wk, sq, wk_t);
    k1_xbar<<<BB * NN, DD, 0, stream>>>(x, mask, wk_t, out);
    gemm64<<<64, 256, 0, stream>>>(out + XB_OFF, DD, Wv, bv, out + Z_OFF);  // Z = Xbar·Wv + bv
    gemm64<<<64, 256, 0, stream>>>(out + Z_OFF, 0, Wo, bo, out + Y_OFF);    // Y = Z·Wo + bo
    k4_broadcast<<<BB * NN * 4, 256, 0, stream>>>(out);
}

// Round 3
// 123.425 us; speedup vs baseline: 1.3877x; 1.3877x over previous
//
#include <hip/hip_runtime.h>
#include <math.h>

#define BB 8
#define NN 64
#define SS 128
#define DD 512
#define HH 8
#define DKK 64
#define NSENT (BB * NN)          // 512
#define SENT_STRIDE (SS * DD)    // 65536 floats per sentence region

// scratch rows inside each sentence's out region (all overwritten by kb_bcast)
#define Y_OFF  0                 // row 0: y (512)
#define Z_OFF  DD                // row 1: z (512)
#define XB_OFF (2 * DD)          // rows 2-9: xbar[8][512]
#define W_OFF  (10 * DD)         // rows 10-11: w[8][128]

// ---------------------------------------------------------------------------
// K0: fold Wk with sent_q: wk_t[h][d] = sum_k Wk[d, h*64+k] * sent_q[h,k]
// (bk is softmax-shift-invariant; Wq/bq dead: token softmax is over a singleton)
// ---------------------------------------------------------------------------
__global__ void precompute_wk(const float* __restrict__ Wk,
                              const float* __restrict__ sq,
                              float* __restrict__ wk_t) {
    const int d = threadIdx.x;
    const int h = blockIdx.x;
    const float4* wrow = (const float4*)(Wk + (size_t)d * DD + h * DKK);
    const float4* sqv  = (const float4*)(sq + h * DKK);
    float acc = 0.f;
#pragma unroll
    for (int k = 0; k < DKK / 4; ++k) {
        float4 w = wrow[k], q = sqv[k];
        acc += w.x * q.x + w.y * q.y + w.z * q.z + w.w * q.w;
    }
    wk_t[h * DD + d] = acc;
}

// ---------------------------------------------------------------------------
// KW: masked exp-weights. One WAVE per token, 8 tokens per wave (wk amortized
// in 64 VGPRs). No LDS, no barriers -> pure x stream.
//   w[sent][h][s] = mask ? exp(x[s]·wk_eff[:,h] / 8) : 0
// ---------------------------------------------------------------------------
__global__ __launch_bounds__(512)
void kw_weights(const float* __restrict__ x, const int* __restrict__ mask,
                const float* __restrict__ wk_t, float* __restrict__ outp)
{
    const int wave = threadIdx.x >> 6;
    const int lane = threadIdx.x & 63;
    const int tok0 = blockIdx.x * 64 + wave * 8;

    const int d0 = lane * 8;
    float4 wkA[HH], wkB[HH];
#pragma unroll
    for (int h = 0; h < HH; ++h) {
        wkA[h] = *(const float4*)(wk_t + h * DD + d0);
        wkB[h] = *(const float4*)(wk_t + h * DD + d0 + 4);
    }
    const int hsel = lane & 7;

#pragma unroll 2
    for (int j = 0; j < 8; ++j) {
        const int tok = tok0 + j;
        const int m = mask[tok];
        const float* xr = x + (size_t)tok * DD + d0;
        float4 xa = *(const float4*)xr;
        float4 xb = *(const float4*)(xr + 4);
        float p[HH];
#pragma unroll
        for (int h = 0; h < HH; ++h)
            p[h] = xa.x * wkA[h].x + xa.y * wkA[h].y + xa.z * wkA[h].z + xa.w * wkA[h].w
                 + xb.x * wkB[h].x + xb.y * wkB[h].y + xb.z * wkB[h].z + xb.w * wkB[h].w;
        // sum within 8-lane groups (each group covers 64 dims)
#pragma unroll
        for (int off = 1; off <= 4; off <<= 1)
#pragma unroll
            for (int h = 0; h < HH; ++h)
                p[h] += __shfl_xor(p[h], off, 64);
        // lane keeps head (lane&7); reduce across the 8 groups
        float v = p[0];
#pragma unroll
        for (int h = 1; h < HH; ++h) v = (hsel == h) ? p[h] : v;
        v += __shfl_xor(v, 8, 64);
        v += __shfl_xor(v, 16, 64);
        v += __shfl_xor(v, 32, 64);
        if (lane < HH) {
            const float e = m ? __expf(v * 0.125f) : 0.f;
            const int sent = tok >> 7, s = tok & (SS - 1);
            outp[(size_t)sent * SENT_STRIDE + W_OFF + hsel * SS + s] = e;
        }
    }
}

// ---------------------------------------------------------------------------
// KX: xbar[sent][h][d] = (sum_s w[h][s] * x[sent][s][d]) / sum_s w[h][s]
// block = (sent, half of dims); 256 threads, thread owns one dim.
// w in 4 KB LDS (uniform broadcast reads); x reads coalesced (LLC-resident).
// ---------------------------------------------------------------------------
__global__ __launch_bounds__(256)
void kx_xbar(const float* __restrict__ x, float* __restrict__ outp)
{
    __shared__ float wl[HH * SS];   // 4 KB
    __shared__ float rsh[HH];

    const int bid  = blockIdx.x;
    const int sent = bid >> 1, half = bid & 1;
    const int t    = threadIdx.x;
    float* base = outp + (size_t)sent * SENT_STRIDE;

    // load w (1024 floats) and compute per-head 1/sum
    float4 wv = *(const float4*)(base + W_OFF + t * 4);
    *(float4*)&wl[t * 4] = wv;
    float ps = wv.x + wv.y + wv.z + wv.w;     // head h = t>>5 (32 threads/head)
#pragma unroll
    for (int off = 1; off <= 16; off <<= 1)
        ps += __shfl_xor(ps, off, 64);
    if ((t & 31) == 0) rsh[t >> 5] = 1.0f / ps;
    __syncthreads();

    const int d = half * 256 + t;
    const float* xp = x + (size_t)sent * SENT_STRIDE + d;
    float acc[HH];
#pragma unroll
    for (int h = 0; h < HH; ++h) acc[h] = 0.f;

#pragma unroll 4
    for (int s0 = 0; s0 < SS; s0 += 4) {
        const float x0 = xp[(size_t)(s0 + 0) * DD];
        const float x1 = xp[(size_t)(s0 + 1) * DD];
        const float x2 = xp[(size_t)(s0 + 2) * DD];
        const float x3 = xp[(size_t)(s0 + 3) * DD];
#pragma unroll
        for (int h = 0; h < HH; ++h) {
            const float4 w4 = *(const float4*)&wl[h * SS + s0];
            acc[h] += w4.x * x0 + w4.y * x1 + w4.z * x2 + w4.w * x3;
        }
    }
#pragma unroll
    for (int h = 0; h < HH; ++h)
        base[XB_OFF + h * DD + d] = acc[h] * rsh[h];
}

// ---------------------------------------------------------------------------
// G: 32x64-tile fp32 GEMM, M=512 (sentence rows, stride SENT_STRIDE), K=512.
// BK=64, 128 blocks (16 mb x 8 nb), 256 thr; global loads issued before the
// barrier so they overlap the previous tile's FMAs.
// G1: A=xbar (a_nb_stride=DD picks head block), B=Wv -> z
// G2: A=z    (a_nb_stride=0),                  B=Wo -> y
// ---------------------------------------------------------------------------
__global__ __launch_bounds__(256)
void gemm_proj(const float* __restrict__ A, const int a_nb_stride,
               const float* __restrict__ B, const float* __restrict__ bias,
               float* __restrict__ C)
{
    __shared__ float Ast[64][33];   // [k][m], padded
    __shared__ float Bs[64][68];    // [k][n], padded

    const int bid = blockIdx.x;
    const int nb = bid & 7, mb = bid >> 3;
    const int t  = threadIdx.x;
    const int tr = t >> 4, tc = t & 15;      // outputs: rows tr*2..+1, cols tc*4..+3
    const int lr = t >> 3, lkq = t & 7;      // A loader: row lr, k-chunk lkq*8
    const int bkr = t >> 2, bcq = t & 3;     // B loader: k-row bkr, col-chunk bcq*16

    const float* Ab = A + (size_t)(mb * 32) * SENT_STRIDE + nb * a_nb_stride;
    const float* Bb = B + nb * 64;

    float ac[2][4];
#pragma unroll
    for (int i = 0; i < 2; ++i)
#pragma unroll
        for (int j = 0; j < 4; ++j) ac[i][j] = 0.f;

    for (int k0 = 0; k0 < DD; k0 += 64) {
        const float* ap = Ab + (size_t)lr * SENT_STRIDE + k0 + lkq * 8;
        float4 a0 = *(const float4*)(ap);
        float4 a1 = *(const float4*)(ap + 4);
        const float* bp = Bb + (size_t)(k0 + bkr) * DD + bcq * 16;
        float4 b0 = *(const float4*)(bp + 0);
        float4 b1 = *(const float4*)(bp + 4);
        float4 b2 = *(const float4*)(bp + 8);
        float4 b3 = *(const float4*)(bp + 12);
        __syncthreads();   // previous tile's LDS reads complete
        Ast[lkq * 8 + 0][lr] = a0.x;
        Ast[lkq * 8 + 1][lr] = a0.y;
        Ast[lkq * 8 + 2][lr] = a0.z;
        Ast[lkq * 8 + 3][lr] = a0.w;
        Ast[lkq * 8 + 4][lr] = a1.x;
        Ast[lkq * 8 + 5][lr] = a1.y;
        Ast[lkq * 8 + 6][lr] = a1.z;
        Ast[lkq * 8 + 7][lr] = a1.w;
        *(float4*)&Bs[bkr][bcq * 16 + 0]  = b0;
        *(float4*)&Bs[bkr][bcq * 16 + 4]  = b1;
        *(float4*)&Bs[bkr][bcq * 16 + 8]  = b2;
        *(float4*)&Bs[bkr][bcq * 16 + 12] = b3;
        __syncthreads();
#pragma unroll
        for (int kk = 0; kk < 64; ++kk) {
            const float a_0 = Ast[kk][tr * 2 + 0];
            const float a_1 = Ast[kk][tr * 2 + 1];
            const float4 b4 = *(const float4*)&Bs[kk][tc * 4];
            ac[0][0] += a_0 * b4.x; ac[0][1] += a_0 * b4.y;
            ac[0][2] += a_0 * b4.z; ac[0][3] += a_0 * b4.w;
            ac[1][0] += a_1 * b4.x; ac[1][1] += a_1 * b4.y;
            ac[1][2] += a_1 * b4.z; ac[1][3] += a_1 * b4.w;
        }
    }

    const float4 bb = *(const float4*)(bias + nb * 64 + tc * 4);
#pragma unroll
    for (int i = 0; i < 2; ++i) {
        float4 o;
        o.x = ac[i][0] + bb.x;
        o.y = ac[i][1] + bb.y;
        o.z = ac[i][2] + bb.z;
        o.w = ac[i][3] + bb.w;
        *(float4*)(C + (size_t)(mb * 32 + tr * 2 + i) * SENT_STRIDE + nb * 64 + tc * 4) = o;
    }
}

// ---------------------------------------------------------------------------
// KB: broadcast y (row 0) to all 128 token rows. 8 blocks/sentence.
// ---------------------------------------------------------------------------
__global__ __launch_bounds__(256)
void kb_bcast(float* __restrict__ outp)
{
    const int sent = blockIdx.x >> 3, q = blockIdx.x & 7;
    float* base = outp + (size_t)sent * SENT_STRIDE;
    const int c  = threadIdx.x & 127;        // float4 column
    const int rh = threadIdx.x >> 7;         // 0..1
    const float4 y = *(const float4*)(base + c * 4);
    float* w0 = base + (size_t)(q * 16 + rh) * DD + c * 4;
#pragma unroll
    for (int i = 0; i < 8; ++i)
        *(float4*)(w0 + (size_t)(i * 2) * DD) = y;
}

extern "C" void kernel_launch(void* const* d_in, const int* in_sizes, int n_in,
                              void* d_out, int out_size, void* d_ws, size_t ws_size,
                              hipStream_t stream) {
    const float* x    = (const float*)d_in[0];
    const int*   mask = (const int*)  d_in[1];
    // d_in[2]=Wq, d_in[3]=bq dead (token softmax over singleton); d_in[5]=bk shift-invariant
    const float* Wk   = (const float*)d_in[4];
    const float* Wv   = (const float*)d_in[6];
    const float* bv   = (const float*)d_in[7];
    const float* sq   = (const float*)d_in[8];
    const float* Wo   = (const float*)d_in[9];
    const float* bo   = (const float*)d_in[10];
    float* out  = (float*)d_out;
    float* wk_t = (float*)d_ws;   // 16 KB

    precompute_wk<<<HH, DD, 0, stream>>>(Wk, sq, wk_t);
    kw_weights<<<(BB * NN * SS) / 64, 512, 0, stream>>>(x, mask, wk_t, out);
    kx_xbar<<<NSENT * 2, 256, 0, stream>>>(x, out);
    gemm_proj<<<128, 256, 0, stream>>>(out + XB_OFF, DD, Wv, bv, out + Z_OFF);
    gemm_proj<<<128, 256, 0, stream>>>(out + Z_OFF, 0, Wo, bo, out + Y_OFF);
    kb_bcast<<<NSENT * 8, 256, 0, stream>>>(out);
}

// Round 4
// 103.749 us; speedup vs baseline: 1.6509x; 1.1897x over previous
//
#include <hip/hip_runtime.h>
#include <math.h>

#define BB 8
#define NN 64
#define SS 128
#define DD 512
#define HH 8
#define DKK 64
#define NSENT (BB * NN)          // 512
#define SENT_STRIDE (SS * DD)    // 65536 floats per sentence of x / out

// d_ws layout (floats)
#define WK_OFF 0                          // wk_t[8][512]        (16 KB)
#define XB_OFF 4096                       // xbar[512][8][512]   (8 MB)
#define Z_OFF  (XB_OFF + NSENT * HH * DD) // z[512][512]         (1 MB)
#define YY_OFF (Z_OFF + NSENT * DD)       // y[512][512]         (1 MB)

// ---------------------------------------------------------------------------
// K0: fold Wk with sent_q: wk_t[h][d] = sum_k Wk[d, h*64+k] * sent_q[h,k]
// (bk is softmax-shift-invariant; Wq/bq dead: token softmax is over a singleton)
// ---------------------------------------------------------------------------
__global__ void precompute_wk(const float* __restrict__ Wk,
                              const float* __restrict__ sq,
                              float* __restrict__ wk_t) {
    const int d = threadIdx.x;
    const int h = blockIdx.x;
    const float4* wrow = (const float4*)(Wk + (size_t)d * DD + h * DKK);
    const float4* sqv  = (const float4*)(sq + h * DKK);
    float acc = 0.f;
#pragma unroll
    for (int k = 0; k < DKK / 4; ++k) {
        float4 w = wrow[k], q = sqv[k];
        acc += w.x * q.x + w.y * q.y + w.z * q.z + w.w * q.w;
    }
    wk_t[h * DD + d] = acc;
}

// ---------------------------------------------------------------------------
// KA: fused exp-weights + xbar, one block per sentence. 512 thr, 4 KB LDS,
// 2 barriers total.
//  ph1: wave w owns tokens w*16..w*16+15; dot x[s]·wk_eff[:,h] via shfl tree;
//       wl[h][s] = mask ? exp(score/8) : 0
//  ph2: thread t owns dim t; acc[h] += wl[h][s]*x[s][t], 8-deep reg prefetch;
//       xbar[sent][h][t] = acc[h] / sum_s wl[h][s]
// ---------------------------------------------------------------------------
__global__ __launch_bounds__(512)
void ka_xbar(const float* __restrict__ x, const int* __restrict__ mask,
             const float* __restrict__ wk_t, float* __restrict__ xbar)
{
    __shared__ float wl[HH][SS];   // 4 KB
    __shared__ float rsh[HH];

    const int sent = blockIdx.x;
    const int t    = threadIdx.x;
    const int wave = t >> 6;
    const int lane = t & 63;
    const float* xs = x + (size_t)sent * SENT_STRIDE;

    // wk fragments: lane owns dims d0..d0+7 for all 8 heads (64 VGPRs)
    const int d0 = lane * 8;
    float4 wkA[HH], wkB[HH];
#pragma unroll
    for (int h = 0; h < HH; ++h) {
        wkA[h] = *(const float4*)(wk_t + h * DD + d0);
        wkB[h] = *(const float4*)(wk_t + h * DD + d0 + 4);
    }
    const int hsel = lane & 7;

    // ---- ph1: 16 tokens per wave, 2 at a time for load ILP ----
    for (int j = 0; j < 16; j += 2) {
        const int s0 = wave * 16 + j;
        const float* xr0 = xs + (size_t)s0 * DD + d0;
        const float* xr1 = xr0 + DD;
        float4 xa0 = *(const float4*)xr0;
        float4 xb0 = *(const float4*)(xr0 + 4);
        float4 xa1 = *(const float4*)xr1;
        float4 xb1 = *(const float4*)(xr1 + 4);
        const int m0 = mask[sent * SS + s0];
        const int m1 = mask[sent * SS + s0 + 1];
        float p0[HH], p1[HH];
#pragma unroll
        for (int h = 0; h < HH; ++h) {
            p0[h] = xa0.x * wkA[h].x + xa0.y * wkA[h].y + xa0.z * wkA[h].z + xa0.w * wkA[h].w
                  + xb0.x * wkB[h].x + xb0.y * wkB[h].y + xb0.z * wkB[h].z + xb0.w * wkB[h].w;
            p1[h] = xa1.x * wkA[h].x + xa1.y * wkA[h].y + xa1.z * wkA[h].z + xa1.w * wkA[h].w
                  + xb1.x * wkB[h].x + xb1.y * wkB[h].y + xb1.z * wkB[h].z + xb1.w * wkB[h].w;
        }
#pragma unroll
        for (int off = 1; off <= 4; off <<= 1) {
#pragma unroll
            for (int h = 0; h < HH; ++h) {
                p0[h] += __shfl_xor(p0[h], off, 64);
                p1[h] += __shfl_xor(p1[h], off, 64);
            }
        }
        float v0 = p0[0], v1 = p1[0];
#pragma unroll
        for (int h = 1; h < HH; ++h) {
            v0 = (hsel == h) ? p0[h] : v0;
            v1 = (hsel == h) ? p1[h] : v1;
        }
#pragma unroll
        for (int off = 8; off <= 32; off <<= 1) {
            v0 += __shfl_xor(v0, off, 64);
            v1 += __shfl_xor(v1, off, 64);
        }
        if (lane < HH) {
            wl[lane][s0]     = m0 ? __expf(v0 * 0.125f) : 0.f;
            wl[lane][s0 + 1] = m1 ? __expf(v1 * 0.125f) : 0.f;
        }
    }
    __syncthreads();

    // ---- per-head 1/sum: wave h reduces wl[h][:] ----
    {
        float v = wl[wave][lane] + wl[wave][lane + 64];
#pragma unroll
        for (int off = 1; off <= 32; off <<= 1)
            v += __shfl_xor(v, off, 64);
        if (lane == 0) rsh[wave] = 1.0f / v;
    }
    __syncthreads();

    // ---- ph2: thread-per-dim accumulate, 8-deep double-buffered prefetch ----
    {
        const float* xp = xs + t;
        float acc[HH];
#pragma unroll
        for (int h = 0; h < HH; ++h) acc[h] = 0.f;

        float xa[8], xb[8];
#pragma unroll
        for (int j = 0; j < 8; ++j) xa[j] = xp[(size_t)j * DD];

        for (int s0 = 0; s0 < SS; s0 += 16) {
#pragma unroll
            for (int j = 0; j < 8; ++j) xb[j] = xp[(size_t)(s0 + 8 + j) * DD];
#pragma unroll
            for (int j = 0; j < 8; ++j) {
                const float xv = xa[j];
#pragma unroll
                for (int h = 0; h < HH; ++h) acc[h] += wl[h][s0 + j] * xv;
            }
            if (s0 + 16 < SS) {
#pragma unroll
                for (int j = 0; j < 8; ++j) xa[j] = xp[(size_t)(s0 + 16 + j) * DD];
            }
#pragma unroll
            for (int j = 0; j < 8; ++j) {
                const float xv = xb[j];
#pragma unroll
                for (int h = 0; h < HH; ++h) acc[h] += wl[h][s0 + 8 + j] * xv;
            }
        }
        float* xbp = xbar + (size_t)sent * (HH * DD) + t;
#pragma unroll
        for (int h = 0; h < HH; ++h)
            xbp[h * DD] = acc[h] * rsh[h];
    }
}

// ---------------------------------------------------------------------------
// KZ/KY: 16x64-tile fp32 GEMM, M=512, K=512, register-prefetched across the
// barrier. 256 blocks (32 mb x 8 nb), 256 thr, thread = (row tr, colgroup tc).
//  KZ: A=xbar (am=4096, a_nb=512 head select), B=Wv, bias=bv -> z
//  KY: A=z    (am=512,  a_nb=0),               B=Wo, bias=bo -> y
// ---------------------------------------------------------------------------
__global__ __launch_bounds__(256)
void gemm_tile(const float* __restrict__ A, const int am_stride, const int a_nb_stride,
               const float* __restrict__ B, const float* __restrict__ bias,
               float* __restrict__ C)
{
    __shared__ float As[64][17];   // [k][m]
    __shared__ float Bs[64][68];   // [k][n]

    const int nb = blockIdx.x & 7, mb = blockIdx.x >> 3;
    const int t  = threadIdx.x;
    const int tr = t >> 4, tc = t & 15;

    const float* Ab = A + (size_t)(mb * 16) * am_stride + nb * a_nb_stride
                        + (size_t)tr * am_stride + tc * 4;
    const float* Bb = B + nb * 64 + (size_t)tr * DD + tc * 4;

    float4 ar = *(const float4*)(Ab);
    float4 br0 = *(const float4*)(Bb);
    float4 br1 = *(const float4*)(Bb + 16 * DD);
    float4 br2 = *(const float4*)(Bb + 32 * DD);
    float4 br3 = *(const float4*)(Bb + 48 * DD);

    float a0 = 0.f, a1 = 0.f, a2 = 0.f, a3 = 0.f;

    for (int k0 = 0; k0 < DD; k0 += 64) {
        As[tc * 4 + 0][tr] = ar.x;
        As[tc * 4 + 1][tr] = ar.y;
        As[tc * 4 + 2][tr] = ar.z;
        As[tc * 4 + 3][tr] = ar.w;
        *(float4*)&Bs[tr +  0][tc * 4] = br0;
        *(float4*)&Bs[tr + 16][tc * 4] = br1;
        *(float4*)&Bs[tr + 32][tc * 4] = br2;
        *(float4*)&Bs[tr + 48][tc * 4] = br3;
        __syncthreads();
        if (k0 + 64 < DD) {       // prefetch next K-tile; overlaps compute below
            ar  = *(const float4*)(Ab + k0 + 64);
            br0 = *(const float4*)(Bb + (size_t)(k0 + 64) * DD);
            br1 = *(const float4*)(Bb + (size_t)(k0 + 80) * DD);
            br2 = *(const float4*)(Bb + (size_t)(k0 + 96) * DD);
            br3 = *(const float4*)(Bb + (size_t)(k0 + 112) * DD);
        }
#pragma unroll
        for (int kk = 0; kk < 64; ++kk) {
            const float av = As[kk][tr];
            const float4 bv4 = *(const float4*)&Bs[kk][tc * 4];
            a0 += av * bv4.x; a1 += av * bv4.y; a2 += av * bv4.z; a3 += av * bv4.w;
        }
        __syncthreads();
    }

    const float4 bb = *(const float4*)(bias + nb * 64 + tc * 4);
    float4 o; o.x = a0 + bb.x; o.y = a1 + bb.y; o.z = a2 + bb.z; o.w = a3 + bb.w;
    *(float4*)(C + (size_t)(mb * 16 + tr) * DD + nb * 64 + tc * 4) = o;
}

// ---------------------------------------------------------------------------
// KB: broadcast y[sent] to all 128 token rows of out. 2048 blocks x 256 thr.
// ---------------------------------------------------------------------------
__global__ __launch_bounds__(256)
void kb_bcast(const float* __restrict__ y, float* __restrict__ outp)
{
    const int sent = blockIdx.x >> 2, q = blockIdx.x & 3;
    const int c4 = threadIdx.x & 127;       // float4 column 0..127
    const int rr = threadIdx.x >> 7;        // 0..1
    const float4 yv = *(const float4*)(y + (size_t)sent * DD + c4 * 4);
    float* w0 = outp + (size_t)sent * SENT_STRIDE + (size_t)(q * 32 + rr) * DD + c4 * 4;
#pragma unroll
    for (int i = 0; i < 16; ++i)
        *(float4*)(w0 + (size_t)(i * 2) * DD) = yv;
}

extern "C" void kernel_launch(void* const* d_in, const int* in_sizes, int n_in,
                              void* d_out, int out_size, void* d_ws, size_t ws_size,
                              hipStream_t stream) {
    const float* x    = (const float*)d_in[0];
    const int*   mask = (const int*)  d_in[1];
    // d_in[2]=Wq, d_in[3]=bq dead (token softmax over singleton); d_in[5]=bk shift-invariant
    const float* Wk   = (const float*)d_in[4];
    const float* Wv   = (const float*)d_in[6];
    const float* bv   = (const float*)d_in[7];
    const float* sq   = (const float*)d_in[8];
    const float* Wo   = (const float*)d_in[9];
    const float* bo   = (const float*)d_in[10];
    float* out = (float*)d_out;
    float* ws  = (float*)d_ws;

    float* wk_t = ws + WK_OFF;
    float* xbar = ws + XB_OFF;
    float* z    = ws + Z_OFF;
    float* y    = ws + YY_OFF;

    precompute_wk<<<HH, DD, 0, stream>>>(Wk, sq, wk_t);
    ka_xbar<<<NSENT, 512, 0, stream>>>(x, mask, wk_t, xbar);
    gemm_tile<<<256, 256, 0, stream>>>(xbar, HH * DD, DD, Wv, bv, z);
    gemm_tile<<<256, 256, 0, stream>>>(z, DD, 0, Wo, bo, y);
    kb_bcast<<<NSENT * 4, 256, 0, stream>>>(y, out);
}